// Round 4
// baseline (176.657 us; speedup 1.0000x reference)
//
#include <hip/hip_runtime.h>
#include <hip/hip_cooperative_groups.h>

namespace cg = cooperative_groups;

#define NATOMS 8192
#define MAXP (64 * NATOMS) /* 524288 */
#define R2CUT 25.0f

constexpr int NC1 = 9;                    // cells per axis (45/5)
constexpr int NCELL = NC1 * NC1 * NC1;    // 729
constexpr int BCAP = 48;                  // bucket capacity (lambda~11, ~1e-16 tail)
constexpr int ROWW = 128;                 // per-row neighbor capacity
constexpr int NBLK = 256;
constexpr int NTHR = 512;
constexpr int RPB = NATOMS / NBLK;        // 32 rows per block
constexpr int GTH = NBLK * NTHR;          // 131072 threads

// Pair predicate must match float32 numpy bit-exactly: no FMA contraction.
__device__ __forceinline__ float d2_exact(float dx, float dy, float dz) {
    return __fadd_rn(__fadd_rn(__fmul_rn(dx, dx), __fmul_rn(dy, dy)),
                     __fmul_rn(dz, dz));
}

// Double-precision cell assign: monotone, and cells>=2 apart => d2>=25 exactly.
__device__ __forceinline__ int cellOf(float v) {
    int c = (int)((double)v * 0.2);
    return c < 0 ? 0 : (c > NC1 - 1 ? NC1 - 1 : c);
}

__global__ void __launch_bounds__(NTHR, 4)
nl_all(const float* __restrict__ pos, const int* __restrict__ batch,
       int* __restrict__ bucketCount, float4* __restrict__ buckets,
       int* __restrict__ counts, float* __restrict__ out) {
    cg::grid_group grid = cg::this_grid();
    const int t = threadIdx.x;
    const int b = blockIdx.x;
    const int gtid = b * NTHR + t;
    const int lane = t & 63;
    const int wave = t >> 6;

    __shared__ unsigned int bm[8][256];            // 8 KB: per-wave j-bitmap
    __shared__ unsigned short rb[RPB][ROWW];       // 8 KB: per-row j-lists
    __shared__ int partial[NTHR];                  // 2 KB: scan ladder
    __shared__ int rowoff[RPB];
    __shared__ int rowcnt[RPB];

    // ---- P1: zero cell counters -------------------------------------------
    if (gtid < NCELL) bucketCount[gtid] = 0;
    grid.sync();

    // ---- P2: init output padding + bin atoms into buckets -----------------
    {
        float4* o4 = (float4*)out;
        const float4 negv  = make_float4(-1.f, -1.f, -1.f, -1.f);
        const float4 zerov = make_float4(0.f, 0.f, 0.f, 0.f);
        // 786432 float4 total; first 262144 (= 2*GTH... = edge_index) -> -1
        o4[gtid]           = negv;   // [0, 131072)
        o4[gtid + GTH]     = negv;   // [131072, 262144)
        o4[gtid + 2 * GTH] = zerov;
        o4[gtid + 3 * GTH] = zerov;
        o4[gtid + 4 * GTH] = zerov;
        o4[gtid + 5 * GTH] = zerov;
        if (gtid < NATOMS) {
            const float x = pos[3 * gtid], y = pos[3 * gtid + 1],
                        z = pos[3 * gtid + 2];
            const int c = (cellOf(z) * NC1 + cellOf(y)) * NC1 + cellOf(x);
            const int slot = atomicAdd(&bucketCount[c], 1);
            if (slot < BCAP)
                buckets[c * BCAP + slot] =
                    make_float4(x, y, z, __int_as_float(gtid));
        }
    }
    grid.sync();

    // ---- P3: neighbor search, 4 rows per wave -----------------------------
    for (int rr = 0; rr < 4; ++rr) {
        const int q = wave * 4 + rr;
        const int i = b * RPB + q;
        unsigned int* sb = bm[wave];
        sb[lane] = 0u; sb[lane + 64] = 0u; sb[lane + 128] = 0u; sb[lane + 192] = 0u;
        const float xi = pos[3 * i], yi = pos[3 * i + 1], zi = pos[3 * i + 2];
        const int bi = batch[i];
        const int cx = cellOf(xi), cy = cellOf(yi), cz = cellOf(zi);
        const int xlo = cx > 0 ? cx - 1 : 0;
        const int nc = (cx < NC1 - 1 ? cx + 1 : NC1 - 1) - xlo + 1;
        for (int dz = -1; dz <= 1; ++dz) {
            const int czz = cz + dz;
            if ((unsigned)czz >= (unsigned)NC1) continue;
            for (int dy = -1; dy <= 1; ++dy) {
                const int cyy = cy + dy;
                if ((unsigned)cyy >= (unsigned)NC1) continue;
                const int c0 = (czz * NC1 + cyy) * NC1 + xlo;
                const int n0 = min(bucketCount[c0], BCAP);
                const int n1 = nc > 1 ? min(bucketCount[c0 + 1], BCAP) : 0;
                const int n2 = nc > 2 ? min(bucketCount[c0 + 2], BCAP) : 0;
                const int m = n0 + n1 + n2;
                for (int k = lane; k < m; k += 64) {
                    int cell, idx;
                    if (k < n0)           { cell = c0;     idx = k; }
                    else if (k < n0 + n1) { cell = c0 + 1; idx = k - n0; }
                    else                  { cell = c0 + 2; idx = k - n0 - n1; }
                    const float4 p = buckets[cell * BCAP + idx];
                    const int j = __float_as_int(p.w);
                    const float dxv = xi - p.x;
                    const float dyv = yi - p.y;
                    const float dzv = zi - p.z;
                    const float d2 = d2_exact(dxv, dyv, dzv);
                    if (d2 < R2CUT && j != i && batch[j] == bi)
                        atomicOr(&sb[j >> 5], 1u << (j & 31));
                }
            }
        }
        // emit ascending-j into LDS row list (canonical order, matches nonzero)
        int total = 0;
#pragma unroll
        for (int g4 = 0; g4 < 4; ++g4) {
            unsigned int w = sb[g4 * 64 + lane];
            const int c = __popc(w);
            int incl = c;
            for (int off = 1; off < 64; off <<= 1) {
                const int u = __shfl_up(incl, off);
                if (lane >= off) incl += u;
            }
            int o = total + incl - c;
            const unsigned int jbase = (unsigned)(g4 * 64 + lane) * 32u;
            while (w) {
                const int bit = __ffs(w) - 1;
                w &= w - 1u;
                if (o < ROWW) rb[q][o] = (unsigned short)(jbase + (unsigned)bit);
                ++o;
            }
            total += __shfl(incl, 63);
        }
        if (lane == 0) {
            const int cv = total > ROWW ? ROWW : total;
            counts[i] = cv;
            rowcnt[q] = cv;
        }
    }
    grid.sync();

    // ---- P4: redundant block-wide scan of counts + scatter own rows -------
    {
        const int4* c4 = (const int4*)counts;
        int4 v0 = c4[4 * t + 0], v1 = c4[4 * t + 1];
        int4 v2 = c4[4 * t + 2], v3 = c4[4 * t + 3];
        const int s = v0.x + v0.y + v0.z + v0.w + v1.x + v1.y + v1.z + v1.w +
                      v2.x + v2.y + v2.z + v2.w + v3.x + v3.y + v3.z + v3.w;
        partial[t] = s;
        __syncthreads();
        for (int off = 1; off < NTHR; off <<= 1) {
            const int u = (t >= off) ? partial[t - off] : 0;
            __syncthreads();
            partial[t] += u;
            __syncthreads();
        }
        // block b's rows 32b..32b+31 are exactly chunks t=2b and t=2b+1
        if ((t >> 1) == b) {
            int vals[16];
            vals[0] = v0.x;  vals[1] = v0.y;  vals[2] = v0.z;  vals[3] = v0.w;
            vals[4] = v1.x;  vals[5] = v1.y;  vals[6] = v1.z;  vals[7] = v1.w;
            vals[8] = v2.x;  vals[9] = v2.y;  vals[10] = v2.z; vals[11] = v2.w;
            vals[12] = v3.x; vals[13] = v3.y; vals[14] = v3.z; vals[15] = v3.w;
            const int qb = (t & 1) * 16;
            int run = partial[t] - s;  // exclusive prefix of counts[16t]
#pragma unroll
            for (int q2 = 0; q2 < 16; ++q2) {
                rowoff[qb + q2] = run;
                run += vals[q2];
            }
        }
        __syncthreads();
    }
    {
        float* __restrict__ outI = out;
        float* __restrict__ outJ = out + MAXP;
        float* __restrict__ outW = out + 2 * MAXP;
        float* __restrict__ outV = out + 3 * MAXP;
        for (int rr = 0; rr < 4; ++rr) {
            const int q = wave * 4 + rr;
            const int i = b * RPB + q;
            const int cnt = rowcnt[q];
            const int base = rowoff[q];
            const float xi = pos[3 * i], yi = pos[3 * i + 1], zi = pos[3 * i + 2];
            const float fi = (float)i;
            for (int k = lane; k < cnt; k += 64) {
                const int j = rb[q][k];
                const float dxv = xi - pos[3 * j];
                const float dyv = yi - pos[3 * j + 1];
                const float dzv = zi - pos[3 * j + 2];
                const float d2 = d2_exact(dxv, dyv, dzv);
                const int slot = base + k;
                if (slot < MAXP) {
                    outI[slot] = fi;
                    outJ[slot] = (float)j;
                    outW[slot] = sqrtf(d2);
                    outV[3 * slot + 0] = dxv;
                    outV[3 * slot + 1] = dyv;
                    outV[3 * slot + 2] = dzv;
                }
            }
        }
    }
}

extern "C" void kernel_launch(void* const* d_in, const int* in_sizes, int n_in,
                              void* d_out, int out_size, void* d_ws, size_t ws_size,
                              hipStream_t stream) {
    const float* pos = (const float*)d_in[0];
    const int* batch = (const int*)d_in[1];
    float* out = (float*)d_out;

    char* ws = (char*)d_ws;
    int* counts       = (int*)ws;                 // 32 KB, 16B-aligned
    int* bucketCount  = (int*)(ws + (32 << 10));  // 4 KB
    float4* buckets   = (float4*)(ws + (64 << 10));  // 729*48*16 = 560 KB

    void* args[] = {(void*)&pos,     (void*)&batch,  (void*)&bucketCount,
                    (void*)&buckets, (void*)&counts, (void*)&out};
    hipLaunchCooperativeKernel(nl_all, dim3(NBLK), dim3(NTHR), args, 0, stream);
}

// Round 5
// 86.231 us; speedup vs baseline: 2.0486x; 2.0486x over previous
//
#include <hip/hip_runtime.h>

#define NATOMS 8192
#define MAXP (64 * NATOMS) /* 524288 */
#define R2CUT 25.0f

constexpr int NC1 = 9;                  // cells per axis (45/5)
constexpr int NCELL = NC1 * NC1 * NC1;  // 729
constexpr int BCAP = 48;                // bucket capacity (max cell occupancy ~28)
constexpr int ROWW = 128;               // per-row neighbor capacity

// Pair predicate must match float32 numpy bit-exactly: no FMA contraction.
__device__ __forceinline__ float d2_exact(float dx, float dy, float dz) {
    return __fadd_rn(__fadd_rn(__fmul_rn(dx, dx), __fmul_rn(dy, dy)),
                     __fmul_rn(dz, dz));
}

// Double-precision cell assign: monotone; cells >=2 apart => d2 >= 25 exactly.
__device__ __forceinline__ int cellOf(float v) {
    int c = (int)((double)v * 0.2);
    return c < 0 ? 0 : (c > NC1 - 1 ? NC1 - 1 : c);
}

// ---------------------------------------------------------------------------
// Single block: LDS histogram gives each atom a slot; scatter into padded
// per-cell buckets (cell*BCAP). No prefix scan needed.
__global__ __launch_bounds__(1024) void bin_all(const float* __restrict__ pos,
                                                int* __restrict__ bucketCount,
                                                float4* __restrict__ buckets) {
    __shared__ unsigned int hist[NCELL];
    const int t = threadIdx.x;
    if (t < NCELL) hist[t] = 0u;
    __syncthreads();
#pragma unroll
    for (int k = 0; k < 8; ++k) {
        const int a = t + k * 1024;
        const float x = pos[3 * a], y = pos[3 * a + 1], z = pos[3 * a + 2];
        const int c = (cellOf(z) * NC1 + cellOf(y)) * NC1 + cellOf(x);
        const int slot = (int)atomicAdd(&hist[c], 1u);
        if (slot < BCAP)
            buckets[c * BCAP + slot] = make_float4(x, y, z, __int_as_float(a));
    }
    __syncthreads();
    if (t < NCELL) bucketCount[t] = (int)hist[t];
}

// ---------------------------------------------------------------------------
// One wave per row i. Candidates from the 9 (dz,dy) x-runs are packed densely
// across lanes; hits OR into a per-wave 8192-bit LDS bitmap, emitted in
// ascending-j order (canonical: matches jnp.nonzero row-major order).
__global__ __launch_bounds__(512) void nl_neigh(const float* __restrict__ pos,
                                                const int* __restrict__ batch,
                                                const int* __restrict__ bucketCount,
                                                const float4* __restrict__ buckets,
                                                int* __restrict__ counts,
                                                unsigned short* __restrict__ rowbuf) {
    __shared__ unsigned int bm[8][256];  // 8 KB, private per wave
    const int t = threadIdx.x;
    const int lane = t & 63;
    const int wave = t >> 6;
    const int i = blockIdx.x * 8 + wave;
    unsigned int* sb = bm[wave];
    sb[lane] = 0u; sb[lane + 64] = 0u; sb[lane + 128] = 0u; sb[lane + 192] = 0u;

    const float xi = pos[3 * i], yi = pos[3 * i + 1], zi = pos[3 * i + 2];
    const int bi = batch[i];
    const int cx = cellOf(xi), cy = cellOf(yi), cz = cellOf(zi);
    const int xlo = cx > 0 ? cx - 1 : 0;
    const int nc = (cx < NC1 - 1 ? cx + 1 : NC1 - 1) - xlo + 1;

    for (int dz = -1; dz <= 1; ++dz) {
        const int czz = cz + dz;
        if ((unsigned)czz >= (unsigned)NC1) continue;
        for (int dy = -1; dy <= 1; ++dy) {
            const int cyy = cy + dy;
            if ((unsigned)cyy >= (unsigned)NC1) continue;
            const int c0 = (czz * NC1 + cyy) * NC1 + xlo;
            const int n0 = min(bucketCount[c0], BCAP);
            const int n1 = nc > 1 ? min(bucketCount[c0 + 1], BCAP) : 0;
            const int n2 = nc > 2 ? min(bucketCount[c0 + 2], BCAP) : 0;
            const int m = n0 + n1 + n2;
            for (int k = lane; k < m; k += 64) {
                int cell, idx;
                if (k < n0)           { cell = c0;     idx = k; }
                else if (k < n0 + n1) { cell = c0 + 1; idx = k - n0; }
                else                  { cell = c0 + 2; idx = k - n0 - n1; }
                const float4 p = buckets[cell * BCAP + idx];
                const int j = __float_as_int(p.w);
                const float dxv = xi - p.x;
                const float dyv = yi - p.y;
                const float dzv = zi - p.z;
                const float d2 = d2_exact(dxv, dyv, dzv);
                if (d2 < R2CUT && j != i && batch[j] == bi)
                    atomicOr(&sb[j >> 5], 1u << (j & 31));
            }
        }
    }

    // Emit ascending-j u16 list to global rowbuf.
    unsigned short* rb = rowbuf + (size_t)i * ROWW;
    int total = 0;
#pragma unroll
    for (int g = 0; g < 4; ++g) {
        unsigned int w = sb[g * 64 + lane];
        const int c = __popc(w);
        int incl = c;
        for (int off = 1; off < 64; off <<= 1) {
            const int u = __shfl_up(incl, off);
            if (lane >= off) incl += u;
        }
        int o = total + incl - c;  // exclusive within row
        const unsigned int jbase = (unsigned)(g * 64 + lane) * 32u;
        while (w) {
            const int bit = __ffs(w) - 1;
            w &= w - 1u;
            if (o < ROWW) rb[o] = (unsigned short)(jbase + (unsigned)bit);
            ++o;
        }
        total += __shfl(incl, 63);
    }
    if (lane == 0) counts[i] = total > ROWW ? ROWW : total;
}

// ---------------------------------------------------------------------------
// 256 blocks x 512. Each block redundantly scans all 8192 counts (L2-resident,
// 32 KB) to derive offsets for its own 32 rows, scatters compacted edge data,
// then cooperatively writes the (-1,-1,0,...) padding tail [total, MAXP).
__global__ __launch_bounds__(512) void nl_scatter(const float* __restrict__ pos,
                                                  const unsigned short* __restrict__ rowbuf,
                                                  const int* __restrict__ counts,
                                                  float* __restrict__ out) {
    constexpr int NTHR = 512;
    __shared__ int partial[NTHR];
    __shared__ int rowoff[32];
    const int t = threadIdx.x;
    const int b = blockIdx.x;
    const int lane = t & 63;
    const int wave = t >> 6;

    const int4* c4 = (const int4*)counts;
    int4 v0 = c4[4 * t + 0], v1 = c4[4 * t + 1];
    int4 v2 = c4[4 * t + 2], v3 = c4[4 * t + 3];
    const int s = v0.x + v0.y + v0.z + v0.w + v1.x + v1.y + v1.z + v1.w +
                  v2.x + v2.y + v2.z + v2.w + v3.x + v3.y + v3.z + v3.w;
    partial[t] = s;
    __syncthreads();
    for (int off = 1; off < NTHR; off <<= 1) {
        const int u = (t >= off) ? partial[t - off] : 0;
        __syncthreads();
        partial[t] += u;
        __syncthreads();
    }
    // block b's rows 32b..32b+31 are exactly count-chunks t=2b and t=2b+1
    if ((t >> 1) == b) {
        int vals[16];
        vals[0] = v0.x;  vals[1] = v0.y;  vals[2] = v0.z;  vals[3] = v0.w;
        vals[4] = v1.x;  vals[5] = v1.y;  vals[6] = v1.z;  vals[7] = v1.w;
        vals[8] = v2.x;  vals[9] = v2.y;  vals[10] = v2.z; vals[11] = v2.w;
        vals[12] = v3.x; vals[13] = v3.y; vals[14] = v3.z; vals[15] = v3.w;
        const int qb = (t & 1) * 16;
        int run = partial[t] - s;  // exclusive prefix of counts[16t]
#pragma unroll
        for (int q = 0; q < 16; ++q) { rowoff[qb + q] = run; run += vals[q]; }
    }
    __syncthreads();
    const int total = partial[NTHR - 1];

    float* __restrict__ outI = out;
    float* __restrict__ outJ = out + MAXP;
    float* __restrict__ outW = out + 2 * MAXP;
    float* __restrict__ outV = out + 3 * MAXP;

    for (int rr = 0; rr < 4; ++rr) {
        const int q = wave * 4 + rr;
        const int i = b * 32 + q;
        const int cnt = counts[i];
        const int base = rowoff[q];
        const float xi = pos[3 * i], yi = pos[3 * i + 1], zi = pos[3 * i + 2];
        const float fi = (float)i;
        const unsigned short* rb = rowbuf + (size_t)i * ROWW;
        for (int k = lane; k < cnt; k += 64) {
            const int j = rb[k];
            const float dxv = xi - pos[3 * j];
            const float dyv = yi - pos[3 * j + 1];
            const float dzv = zi - pos[3 * j + 2];
            const float d2 = d2_exact(dxv, dyv, dzv);
            const int slot = base + k;
            if (slot < MAXP) {
                outI[slot] = fi;
                outJ[slot] = (float)j;
                outW[slot] = sqrtf(d2);
                outV[3 * slot + 0] = dxv;
                outV[3 * slot + 1] = dyv;
                outV[3 * slot + 2] = dzv;
            }
        }
    }

    // Padding tail: slots [total, MAXP) across the whole grid.
    const int g = b * NTHR + t;              // 0..131071
    for (int sl = total + g; sl < MAXP; sl += 256 * NTHR) {
        outI[sl] = -1.f;
        outJ[sl] = -1.f;
        outW[sl] = 0.f;
        outV[3 * sl + 0] = 0.f;
        outV[3 * sl + 1] = 0.f;
        outV[3 * sl + 2] = 0.f;
    }
}

// ---------------------------------------------------------------------------
extern "C" void kernel_launch(void* const* d_in, const int* in_sizes, int n_in,
                              void* d_out, int out_size, void* d_ws, size_t ws_size,
                              hipStream_t stream) {
    const float* pos = (const float*)d_in[0];
    const int* batch = (const int*)d_in[1];
    float* out = (float*)d_out;

    char* ws = (char*)d_ws;
    int* counts            = (int*)ws;                        // 32 KB
    int* bucketCount       = (int*)(ws + (32 << 10));         // 4 KB
    float4* buckets        = (float4*)(ws + (64 << 10));      // 560 KB
    unsigned short* rowbuf = (unsigned short*)(ws + (640 << 10));  // 2 MB

    bin_all<<<1, 1024, 0, stream>>>(pos, bucketCount, buckets);
    nl_neigh<<<NATOMS / 8, 512, 0, stream>>>(pos, batch, bucketCount, buckets,
                                             counts, rowbuf);
    nl_scatter<<<256, 512, 0, stream>>>(pos, rowbuf, counts, out);
}